// Round 9
// baseline (218.675 us; speedup 1.0000x reference)
//
#include <hip/hip_runtime.h>
#include <hip/hip_bf16.h>

typedef __attribute__((ext_vector_type(8))) __bf16 bf16x8;
typedef __attribute__((ext_vector_type(4))) float f32x4;
typedef __attribute__((ext_vector_type(4))) int   i32x4;
typedef unsigned short u16;

// B=2, N=2048, D_MODEL=512, H=8, DK=DV=64. I/O f32; ws intermediates bf16.
// ws (u16 elems), 10 segs x 2M:
//  0 qA  1 qB  2 k1  3 k2   (head-major: [b*8+h][n][64])
//  4 v1^T 5 v2^T            ([b*512+h*64+d][token])
//  6 regions_bf (later O1 token-major)  7 grids_bf (later O2)  8 interests_bf
//  9 weights: Wq@0 Wk@262144 Wv@524288 Wq12@786432 Wo1@1048576 Wo2@1310720
#define WS_SEG 2097152

static __device__ __forceinline__ u16 f2b(float f) {
  __hip_bfloat16 h = __float2bfloat16(f);  // RNE
  return __builtin_bit_cast(u16, h);
}
static __device__ __forceinline__ i32x4 cvt8(const float* __restrict__ p) {
  float4 a = *(const float4*)p;
  float4 b = *(const float4*)(p + 4);
  union { i32x4 v; u16 u[8]; } r;
  r.u[0]=f2b(a.x); r.u[1]=f2b(a.y); r.u[2]=f2b(a.z); r.u[3]=f2b(a.w);
  r.u[4]=f2b(b.x); r.u[5]=f2b(b.y); r.u[6]=f2b(b.z); r.u[7]=f2b(b.w);
  return r.v;
}
static __device__ __forceinline__ float fexp2(float x) {
  float r; asm("v_exp_f32 %0, %1" : "=v"(r) : "v"(x)); return r;
}
template<int C>
static __device__ __forceinline__ float dppf(float x) {
  int v = __builtin_amdgcn_update_dpp(__builtin_bit_cast(int, x),
                                      __builtin_bit_cast(int, x), C, 0xF, 0xF, false);
  return __builtin_bit_cast(float, v);
}
static __device__ __forceinline__ float rowsum16(float x) {
  x += dppf<0xB1>(x);    // xor1
  x += dppf<0x4E>(x);    // xor2
  x += dppf<0x141>(x);   // row_half_mirror
  x += dppf<0x140>(x);   // row_mirror
  return x;
}
// async 16B global -> LDS (dest = wave-uniform base + lane*16)
static __device__ __forceinline__ void gld16(const u16* gp, u16* lp) {
  __builtin_amdgcn_global_load_lds(
      (const __attribute__((address_space(1))) void*)gp,
      (__attribute__((address_space(3))) void*)lp, 16, 0, 0);
}

// ---------------------------------------------------------------------------
// Pre-convert f32 -> bf16 into ws (activations + weights)
// ---------------------------------------------------------------------------
__global__ __launch_bounds__(256) void convert_kernel(
    const float* __restrict__ regions, const float* __restrict__ grids,
    const float* __restrict__ interests,
    const float* __restrict__ Wq, const float* __restrict__ Wk,
    const float* __restrict__ Wv, const float* __restrict__ Wq12,
    const float* __restrict__ Wo1, const float* __restrict__ Wo2,
    u16* __restrict__ ws)
{
  const size_t i = (size_t)(blockIdx.x * 256 + threadIdx.x) * 8;
  const float* s; u16* d;
  if (i < 2097152)      { s = regions   + i;           d = ws + 6 * WS_SEG + i; }
  else if (i < 4194304) { s = grids     + (i - 2097152); d = ws + 7 * WS_SEG + (i - 2097152); }
  else if (i < 6291456) { s = interests + (i - 4194304); d = ws + 8 * WS_SEG + (i - 4194304); }
  else {
    const size_t j = i - 6291456;          // 0 .. 1572863
    d = ws + 9 * WS_SEG + j;
    if (j < 262144)       s = Wq  + j;
    else if (j < 524288)  s = Wk  + (j - 262144);
    else if (j < 786432)  s = Wv  + (j - 524288);
    else if (j < 1048576) s = Wq12+ (j - 786432);
    else if (j < 1310720) s = Wo1 + (j - 1048576);
    else                  s = Wo2 + (j - 1310720);
  }
  *(i32x4*)d = cvt8(s);
}

// ---------------------------------------------------------------------------
// bt-GEMM, MTxNT tile, BK=64, 4 waves (2x2), single-buffered m97-style loop,
// global_load_lds staging with XOR-swizzled stride-64 LDS rows.
// phase 0 (128x64, grid (8,32,4)): z0 qA (K=1024 concat), z1 qB,
//                                  z2 k1 (*scale*log2e*aw), z3 k2
// phase 2 (128x64, grid (4,64,2)): v^T = Wv . act^T  (A=weights rows=hd,
//                                  B=activation rows=tokens)
// phase 1 (64x64,  grid (8,64,2)): out = O_z @ Wo_z^T + bo_z -> f32 d_out
// ---------------------------------------------------------------------------
template<int MT, int NT>
__global__ __launch_bounds__(256, 4) void gemm_all(
    const float* __restrict__ aw,
    const float* __restrict__ bq,  const float* __restrict__ bk,
    const float* __restrict__ bv,  const float* __restrict__ bq12,
    const float* __restrict__ bo1, const float* __restrict__ bo2,
    u16* __restrict__ ws, float* __restrict__ out, int phase)
{
  constexpr int MFR = MT / 32;   // m-frags per wave
  constexpr int NFR = NT / 32;   // n-frags per wave
  __shared__ u16 SM[(MT + NT) * 64];
  u16* As = SM;
  u16* Bs = SM + MT * 64;

  const u16* regs_bf = ws + 6 * WS_SEG;
  const u16* grid_bf = ws + 7 * WS_SEG;
  const u16* intr_bf = ws + 8 * WS_SEG;
  const u16* Wt      = ws + 9 * WS_SEG;

  const u16 *A1 = nullptr, *A2 = nullptr, *B1 = nullptr, *B2 = nullptr;
  const float *bias1 = nullptr, *bias2 = nullptr;
  u16* dst16 = nullptr;
  float* dst32 = nullptr;
  int KT = 512, epi = 0;
  const int z = blockIdx.z;
  if (phase == 0) {
    if (z == 0)      { A1=intr_bf; A2=grid_bf; B1=Wt; B2=Wt+786432; KT=1024; bias1=bq; bias2=bq12; epi=0; dst16=ws+0*WS_SEG; }
    else if (z == 1) { A1=intr_bf; A2=regs_bf; B1=Wt; B2=Wt+786432; KT=1024; bias1=bq; bias2=bq12; epi=0; dst16=ws+1*WS_SEG; }
    else if (z == 2) { A1=regs_bf; B1=Wt+262144; bias1=bk; epi=1; dst16=ws+2*WS_SEG; }
    else             { A1=grid_bf; B1=Wt+262144; bias1=bk; epi=1; dst16=ws+3*WS_SEG; }
  } else if (phase == 2) {
    // A = Wv (rows = hd), B = activation (rows = tokens)
    if (z == 0) { A1=Wt+524288; B1=regs_bf; bias1=bv; epi=3; dst16=ws+4*WS_SEG; }
    else        { A1=Wt+524288; B1=grid_bf; bias1=bv; epi=3; dst16=ws+5*WS_SEG; }
  } else {
    if (z == 0) { A1=ws+6*WS_SEG; B1=Wt+1048576; bias1=bo1; epi=2; dst32=out; }
    else        { A1=ws+7*WS_SEG; B1=Wt+1310720; bias1=bo2; epi=2; dst32=out + 2097152; }
  }

  const int t = threadIdx.x;
  const int lane = t & 63, w = t >> 6;
  const int l15 = lane & 15, q4 = lane >> 4;
  // phase 2: A-rows tiled by grid.x, B-rows by grid.y (transposed mapping)
  const int m0 = (phase == 2 ? blockIdx.x : blockIdx.y) * MT;
  const int j0 = (phase == 2 ? blockIdx.y : blockIdx.x) * NT;
  const int ro = (w >> 1) * (MT / 2), co = (w & 1) * (NT / 2);

  f32x4 acc[MFR][NFR];
  for (int i = 0; i < MFR; i++)
    for (int j = 0; j < NFR; j++) acc[i][j] = (f32x4){0.f, 0.f, 0.f, 0.f};

  for (int k0 = 0; k0 < KT; k0 += 64) {
    const u16* pa = A1; const u16* pb = B1; int kk = k0;
    if (kk >= 512) { pa = A2; pb = B2; kk -= 512; }   // concat-K second half
    __syncthreads();
#pragma unroll
    for (int c = 0; c < MFR; c++) {              // A: MT/8 chunks of 1 KB
      const int cidx = w * MFR + c;
      const int row = cidx * 8 + (lane >> 3);
      const int cg = (lane & 7) ^ (row & 7);
      gld16(&pa[(size_t)(m0 + row) * 512 + kk + cg * 8], &As[cidx * 512]);
    }
#pragma unroll
    for (int c = 0; c < NFR; c++) {              // B: NT/8 chunks
      const int cidx = w * NFR + c;
      const int row = cidx * 8 + (lane >> 3);
      const int cg = (lane & 7) ^ (row & 7);
      gld16(&pb[(size_t)(j0 + row) * 512 + kk + cg * 8], &Bs[cidx * 512]);
    }
    __syncthreads();
#pragma unroll
    for (int h = 0; h < 2; h++) {
      bf16x8 af[MFR], bfr[NFR];
#pragma unroll
      for (int i = 0; i < MFR; i++) {
        const int r = ro + i * 16 + l15;
        af[i] = *(const bf16x8*)&As[r * 64 + (((h * 4 + q4) ^ (r & 7)) * 8)];
      }
#pragma unroll
      for (int i = 0; i < NFR; i++) {
        const int r = co + i * 16 + l15;
        bfr[i] = *(const bf16x8*)&Bs[r * 64 + (((h * 4 + q4) ^ (r & 7)) * 8)];
      }
#pragma unroll
      for (int mt = 0; mt < MFR; mt++)
#pragma unroll
        for (int nt = 0; nt < NFR; nt++)
          acc[mt][nt] = __builtin_amdgcn_mfma_f32_16x16x32_bf16(af[mt], bfr[nt], acc[mt][nt], 0, 0, 0);
    }
  }

  if (epi == 2) {
    // f32 output, scalar dword stores (coalesced across l15)
#pragma unroll
    for (int nt = 0; nt < NFR; nt++) {
      const int j = j0 + co + nt * 16 + l15;
      const float bsum = bias1[j];
#pragma unroll
      for (int mt = 0; mt < MFR; mt++)
#pragma unroll
        for (int r = 0; r < 4; r++) {
          const int m = m0 + ro + mt * 16 + q4 * 4 + r;
          dst32[m * 512 + j] = acc[mt][nt][r] + bsum;
        }
    }
    return;
  }

  // bf16 outputs: LDS round-trip (stride-40 rows, conflict-free) -> dwordx4.
  __syncthreads();                     // SM dead; reuse
  u16* Es = SM + w * (MT / 2) * 40;    // per-wave (MT/2) x (NT/2 <= 40) tile

  if (epi == 3) {
    // tile rows = hd (m0+ro+rr), cols = token (j0+co+..)
#pragma unroll
    for (int mt = 0; mt < MFR; mt++)
#pragma unroll
      for (int r = 0; r < 4; r++) {
        const int rr = mt * 16 + q4 * 4 + r;
        const float bias = bias1[m0 + ro + rr];
#pragma unroll
        for (int nt = 0; nt < NFR; nt++)
          Es[rr * 40 + nt * 16 + l15] = f2b(acc[mt][nt][r] + bias);
      }
  } else {
    float bsum4[NFR];
#pragma unroll
    for (int nt = 0; nt < NFR; nt++) {
      const int j = j0 + co + nt * 16 + l15;
      bsum4[nt] = bias1[j] + (bias2 ? bias2[j] : 0.f);
    }
#pragma unroll
    for (int mt = 0; mt < MFR; mt++)
#pragma unroll
      for (int r = 0; r < 4; r++) {
        const int rr = mt * 16 + q4 * 4 + r;
        const float awm = (epi == 1) ? 0.18033688f * aw[m0 + ro + rr] : 1.f;
#pragma unroll
        for (int nt = 0; nt < NFR; nt++)
          Es[rr * 40 + nt * 16 + l15] = f2b((acc[mt][nt][r] + bsum4[nt]) * awm);
      }
  }
  asm volatile("s_waitcnt lgkmcnt(0)" ::: "memory");  // wave-local RAW on Es

  // read back: 4 lanes per row (NT/2 = 32 cols = 64 B), 16 rows per instr
#pragma unroll
  for (int g = 0; g < MT / 32; g++) {
    const int rr2 = g * 16 + (lane >> 2);
    i32x4 val = *(const i32x4*)&Es[rr2 * 40 + (lane & 3) * 8];
    if (epi == 3) {
      const int hd = m0 + ro + rr2;
      const int token0 = j0 + co;
      *(i32x4*)&dst16[((size_t)(token0 >> 11) * 512 + hd) * 2048 + (token0 & 2047) + (lane & 3) * 8] = val;
    } else {
      // head-major q/k: row = token, cols = within-head d
      const int token = m0 + ro + rr2;
      const int bb = token >> 11, nn = token & 2047;
      const int hd0 = j0 + co;
      const int hh = hd0 >> 6, db = hd0 & 63;
      *(i32x4*)&dst16[((size_t)(bb * 8 + hh) * 2048 + nn) * 64 + db + (lane & 3) * 8] = val;
    }
  }
}

// ---------------------------------------------------------------------------
// Flash attention, fixed-max streaming softmax (exp2 domain, M=16 folded into
// mask bias). Block = 64 q-rows of one (path,b,h); wave = 16 rows.
// Grid (32,16,2) = 1024 blocks -> 4 blocks/CU. Single-buffered K/V staging.
// ---------------------------------------------------------------------------
__global__ __launch_bounds__(256, 4) void attn_kernel(
    const int* __restrict__ mask_r, const int* __restrict__ mask_g,
    u16* __restrict__ ws)
{
  const int qt = blockIdx.x, bh = blockIdx.y, path = blockIdx.z;
  const int b = bh >> 3, h = bh & 7;
  const u16* Q  = (path ? ws + 1 * WS_SEG : ws + 0 * WS_SEG) + (size_t)bh * (2048 * 64) + qt * 64 * 64;
  const u16* K  = (path ? ws + 3 * WS_SEG : ws + 2 * WS_SEG) + (size_t)bh * (2048 * 64);
  const u16* Vg = (path ? ws + 5 * WS_SEG : ws + 4 * WS_SEG) + (size_t)(b * 512 + h * 64) * 2048;
  const int* mask = (path ? mask_g : mask_r) + b * 2048;
  u16* O = (path ? ws + 7 * WS_SEG : ws + 6 * WS_SEG) + (size_t)(b * 2048 + qt * 64) * 512 + h * 64;

  __shared__ u16 Ks[64 * 64];     // [key][d], swizzled chunks
  __shared__ u16 Vs[64 * 64];     // [d][key], swizzled chunks
  __shared__ u16 Ps[64 * 64];     // XOR-swizzled P round-trip / O epilogue
  __shared__ float Ms[2048];      // mask bias - 16 (fixed max)

  const int t = threadIdx.x, lane = t & 63, w = t >> 6;
  const int l15 = lane & 15, q4 = lane >> 4;

  {
    const int4 a = *(const int4*)&mask[t * 8];
    const int4 c = *(const int4*)&mask[t * 8 + 4];
    float4 f1, f2v;
    f1.x = (a.x ? -1e30f : 0.f) - 16.f; f1.y = (a.y ? -1e30f : 0.f) - 16.f;
    f1.z = (a.z ? -1e30f : 0.f) - 16.f; f1.w = (a.w ? -1e30f : 0.f) - 16.f;
    f2v.x = (c.x ? -1e30f : 0.f) - 16.f; f2v.y = (c.y ? -1e30f : 0.f) - 16.f;
    f2v.z = (c.z ? -1e30f : 0.f) - 16.f; f2v.w = (c.w ? -1e30f : 0.f) - 16.f;
    *(float4*)&Ms[t * 8] = f1;
    *(float4*)&Ms[t * 8 + 4] = f2v;
  }

  bf16x8 qf[2];
  {
    const int qrow = w * 16 + l15;
    qf[0] = *(const bf16x8*)&Q[qrow * 64 + q4 * 8];
    qf[1] = *(const bf16x8*)&Q[qrow * 64 + 32 + q4 * 8];
  }

  float l_run[4];
  f32x4 o_acc[4];
#pragma unroll
  for (int r = 0; r < 4; r++) l_run[r] = 0.f;
#pragma unroll
  for (int d = 0; d < 4; d++) o_acc[d] = (f32x4){0.f, 0.f, 0.f, 0.f};

  for (int kt = 0; kt < 32; kt++) {
    __syncthreads();
#pragma unroll
    for (int c = 0; c < 2; c++) {           // stage K and V^T (8 KB each)
      const int cidx = w * 2 + c;
      const int row = cidx * 8 + (lane >> 3);
      const int cg = (lane & 7) ^ (row & 7);
      gld16(&K[(size_t)(kt * 64 + row) * 64 + cg * 8], &Ks[cidx * 512]);
      gld16(&Vg[(size_t)row * 2048 + kt * 64 + cg * 8], &Vs[cidx * 512]);
    }
    __syncthreads();

    // S = Q K^T (scale*log2e*aw pre-folded into K)
    f32x4 s[4];
#pragma unroll
    for (int nt = 0; nt < 4; nt++) s[nt] = (f32x4){0.f, 0.f, 0.f, 0.f};
#pragma unroll
    for (int nt = 0; nt < 4; nt++)
#pragma unroll
      for (int ss = 0; ss < 2; ss++) {
        const int r = nt * 16 + l15;
        bf16x8 kf = *(const bf16x8*)&Ks[r * 64 + (((ss * 4 + q4) ^ (r & 7)) * 8)];
        s[nt] = __builtin_amdgcn_mfma_f32_16x16x32_bf16(qf[ss], kf, s[nt], 0, 0, 0);
      }

    // p = exp2(s + maskbias - 16); accumulate per-lane l; no max tracking
#pragma unroll
    for (int nt = 0; nt < 4; nt++) {
      const float bias = Ms[kt * 64 + nt * 16 + l15];
#pragma unroll
      for (int r = 0; r < 4; r++) {
        const float p = fexp2(s[nt][r] + bias);
        s[nt][r] = p;
        l_run[r] += p;
      }
    }

    // P: C-layout -> A-layout via XOR-swizzled per-wave LDS round trip
#pragma unroll
    for (int nt = 0; nt < 4; nt++) {
      const int cg = 2 * nt + (l15 >> 3);
#pragma unroll
      for (int r = 0; r < 4; r++) {
        const int row = w * 16 + q4 * 4 + r;
        Ps[row * 64 + ((cg ^ (row & 7)) * 8) + (l15 & 7)] = f2b(s[nt][r]);
      }
    }
    asm volatile("s_waitcnt lgkmcnt(0)" ::: "memory");  // wave-local RAW on Ps

    // O += P V
#pragma unroll
    for (int ss = 0; ss < 2; ss++) {
      const int row = w * 16 + l15;
      const int cg = (4 * ss + q4) ^ (row & 7);
      bf16x8 pf = *(const bf16x8*)&Ps[row * 64 + cg * 8];
#pragma unroll
      for (int dt = 0; dt < 4; dt++) {
        const int r = dt * 16 + l15;
        bf16x8 vf = *(const bf16x8*)&Vs[r * 64 + (((ss * 4 + q4) ^ (r & 7)) * 8)];
        o_acc[dt] = __builtin_amdgcn_mfma_f32_16x16x32_bf16(pf, vf, o_acc[dt], 0, 0, 0);
      }
    }
  }

  // O epilogue: normalize, LDS round-trip (wave-local region of Ps), dwordx4
  float inv[4];
#pragma unroll
  for (int r = 0; r < 4; r++) inv[r] = 1.f / rowsum16(l_run[r]);

#pragma unroll
  for (int r = 0; r < 4; r++) {
    const int row = w * 16 + q4 * 4 + r;
#pragma unroll
    for (int dt = 0; dt < 4; dt++)
      Ps[row * 64 + (((dt * 2 + (l15 >> 3)) ^ (row & 7)) * 8) + (l15 & 7)] =
          f2b(o_acc[dt][r] * inv[r]);
  }
  asm volatile("s_waitcnt lgkmcnt(0)" ::: "memory");
#pragma unroll
  for (int g = 0; g < 2; g++) {
    const int rl = w * 16 + g * 8 + (lane >> 3);
    i32x4 val = *(const i32x4*)&Ps[rl * 64 + (((lane & 7) ^ (rl & 7)) * 8)];
    *(i32x4*)&O[(size_t)rl * 512 + (lane & 7) * 8] = val;
  }
}

extern "C" void kernel_launch(void* const* d_in, const int* in_sizes, int n_in,
                              void* d_out, int out_size, void* d_ws, size_t ws_size,
                              hipStream_t stream) {
  const float* regions   = (const float*)d_in[0];
  const float* grids     = (const float*)d_in[1];
  const float* interests = (const float*)d_in[2];
  const int*   mask_r    = (const int*)d_in[3];
  const int*   mask_g    = (const int*)d_in[4];
  const float* aw        = (const float*)d_in[5];
  const float* Wq  = (const float*)d_in[6];  const float* bq  = (const float*)d_in[7];
  const float* Wk  = (const float*)d_in[8];  const float* bk  = (const float*)d_in[9];
  const float* Wv  = (const float*)d_in[10]; const float* bv  = (const float*)d_in[11];
  const float* Wq12= (const float*)d_in[12]; const float* bq12= (const float*)d_in[13];
  const float* Wo1 = (const float*)d_in[14]; const float* bo1 = (const float*)d_in[15];
  const float* Wo2 = (const float*)d_in[16]; const float* bo2 = (const float*)d_in[17];
  u16*   ws  = (u16*)d_ws;
  float* out = (float*)d_out;

  // 0) f32 -> bf16 pre-convert (activations + weights)
  convert_kernel<<<3840, 256, 0, stream>>>(regions, grids, interests,
      Wq, Wk, Wv, Wq12, Wo1, Wo2, ws);
  // 1a) q/k projections (128x64 tiles, 1024 blocks)
  gemm_all<128, 64><<<dim3(8, 32, 4), 256, 0, stream>>>(aw, bq, bk, bv, bq12,
      bo1, bo2, ws, out, 0);
  // 1b) v^T projections (128 hd x 64 token tiles, 512 blocks)
  gemm_all<128, 64><<<dim3(4, 64, 2), 256, 0, stream>>>(aw, bq, bk, bv, bq12,
      bo1, bo2, ws, out, 2);
  // 2) flash attention (64-row Q tiles, 1024 blocks)
  attn_kernel<<<dim3(32, 16, 2), 256, 0, stream>>>(mask_r, mask_g, ws);
  // 3) output projections (64x64 tiles, 1024 blocks) -> d_out (f32)
  gemm_all<64, 64><<<dim3(8, 64, 2), 256, 0, stream>>>(aw, bq, bk, bv, bq12,
      bo1, bo2, ws, out, 1);
}

// Round 10
// 194.537 us; speedup vs baseline: 1.1241x; 1.1241x over previous
//
#include <hip/hip_runtime.h>
#include <hip/hip_bf16.h>

typedef __attribute__((ext_vector_type(8))) __bf16 bf16x8;
typedef __attribute__((ext_vector_type(4))) float f32x4;
typedef __attribute__((ext_vector_type(4))) int   i32x4;
typedef unsigned short u16;

// B=2, N=2048, D_MODEL=512, H=8, DK=DV=64. I/O f32; ws intermediates bf16.
// ws (u16 elems), 10 segs x 2M:
//  0 qA  1 qB  2 k1  3 k2   (head-major: [b*8+h][n][64])
//  4 v1^T 5 v2^T            ([b*512+h*64+d][token])
//  6 regions_bf (later O1 token-major)  7 grids_bf (later O2)  8 interests_bf
//  9 weights: Wq@0 Wk@262144 Wv@524288 Wq12@786432 Wo1@1048576 Wo2@1310720
#define WS_SEG 2097152

static __device__ __forceinline__ u16 f2b(float f) {
  __hip_bfloat16 h = __float2bfloat16(f);  // RNE
  return __builtin_bit_cast(u16, h);
}
static __device__ __forceinline__ i32x4 cvt8(const float* __restrict__ p) {
  float4 a = *(const float4*)p;
  float4 b = *(const float4*)(p + 4);
  union { i32x4 v; u16 u[8]; } r;
  r.u[0]=f2b(a.x); r.u[1]=f2b(a.y); r.u[2]=f2b(a.z); r.u[3]=f2b(a.w);
  r.u[4]=f2b(b.x); r.u[5]=f2b(b.y); r.u[6]=f2b(b.z); r.u[7]=f2b(b.w);
  return r.v;
}
static __device__ __forceinline__ float fexp2(float x) {
  float r; asm("v_exp_f32 %0, %1" : "=v"(r) : "v"(x)); return r;
}
template<int C>
static __device__ __forceinline__ float dppf(float x) {
  int v = __builtin_amdgcn_update_dpp(__builtin_bit_cast(int, x),
                                      __builtin_bit_cast(int, x), C, 0xF, 0xF, false);
  return __builtin_bit_cast(float, v);
}
static __device__ __forceinline__ float rowsum16(float x) {
  x += dppf<0xB1>(x);    // xor1
  x += dppf<0x4E>(x);    // xor2
  x += dppf<0x141>(x);   // row_half_mirror
  x += dppf<0x140>(x);   // row_mirror
  return x;
}
// async 16B global -> LDS (dest = wave-uniform base + lane*16)
static __device__ __forceinline__ void gld16(const u16* gp, u16* lp) {
  __builtin_amdgcn_global_load_lds(
      (const __attribute__((address_space(1))) void*)gp,
      (__attribute__((address_space(3))) void*)lp, 16, 0, 0);
}

// ---------------------------------------------------------------------------
// Pre-convert f32 -> bf16 into ws (activations + weights)
// ---------------------------------------------------------------------------
__global__ __launch_bounds__(256) void convert_kernel(
    const float* __restrict__ regions, const float* __restrict__ grids,
    const float* __restrict__ interests,
    const float* __restrict__ Wq, const float* __restrict__ Wk,
    const float* __restrict__ Wv, const float* __restrict__ Wq12,
    const float* __restrict__ Wo1, const float* __restrict__ Wo2,
    u16* __restrict__ ws)
{
  const size_t i = (size_t)(blockIdx.x * 256 + threadIdx.x) * 8;
  const float* s; u16* d;
  if (i < 2097152)      { s = regions   + i;           d = ws + 6 * WS_SEG + i; }
  else if (i < 4194304) { s = grids     + (i - 2097152); d = ws + 7 * WS_SEG + (i - 2097152); }
  else if (i < 6291456) { s = interests + (i - 4194304); d = ws + 8 * WS_SEG + (i - 4194304); }
  else {
    const size_t j = i - 6291456;          // 0 .. 1572863
    d = ws + 9 * WS_SEG + j;
    if (j < 262144)       s = Wq  + j;
    else if (j < 524288)  s = Wk  + (j - 262144);
    else if (j < 786432)  s = Wv  + (j - 524288);
    else if (j < 1048576) s = Wq12+ (j - 786432);
    else if (j < 1310720) s = Wo1 + (j - 1048576);
    else                  s = Wo2 + (j - 1310720);
  }
  *(i32x4*)d = cvt8(s);
}

// ---------------------------------------------------------------------------
// bt-GEMM, MTx128 tile, BK=64, 4 waves, single-buffered m97-style loop,
// global_load_lds staging, XOR-swizzled stride-64 LDS rows.
// 1D grid, XCD swizzle: id = m_idx + NM*(j_idx + 4*z)  ->  id%8 == m_idx%8
// phase 0 (MT=128, NM=32): z0 qA (K=1024 concat), z1 qB, z2 k1 (*s*log2e*aw),
//                          z3 k2, z4 v1^T (swapped), z5 v2^T
// phase 1 (MT=64,  NM=64): z0/z1 out = O_z @ Wo_z^T + bo_z -> f32 d_out
// ---------------------------------------------------------------------------
template<int MT, int NM>
__global__ __launch_bounds__(256, 2) void gemm_all(
    const float* __restrict__ aw,
    const float* __restrict__ bq,  const float* __restrict__ bk,
    const float* __restrict__ bv,  const float* __restrict__ bq12,
    const float* __restrict__ bo1, const float* __restrict__ bo2,
    u16* __restrict__ ws, float* __restrict__ out, int phase)
{
  constexpr int MFR = MT / 32;       // m-frags per wave
  __shared__ u16 SM[(MT + 128) * 64];
  u16* As = SM;
  u16* Bs = SM + MT * 64;

  const u16* regs_bf = ws + 6 * WS_SEG;
  const u16* grid_bf = ws + 7 * WS_SEG;
  const u16* intr_bf = ws + 8 * WS_SEG;
  const u16* Wt      = ws + 9 * WS_SEG;

  // 1D grid decode with XCD swizzle
  const int id = blockIdx.x;
  const int m_idx = id % NM;
  const int rest  = id / NM;
  const int j_idx = rest & 3;
  const int z     = rest >> 2;

  const u16 *A1 = nullptr, *A2 = nullptr, *B1 = nullptr, *B2 = nullptr;
  const float *bias1 = nullptr, *bias2 = nullptr;
  u16* dst16 = nullptr;
  float* dst32 = nullptr;
  int KT = 512, epi = 0;
  if (phase == 0) {
    if (z == 0)      { A1=intr_bf; A2=grid_bf; B1=Wt; B2=Wt+786432; KT=1024; bias1=bq; bias2=bq12; epi=0; dst16=ws+0*WS_SEG; }
    else if (z == 1) { A1=intr_bf; A2=regs_bf; B1=Wt; B2=Wt+786432; KT=1024; bias1=bq; bias2=bq12; epi=0; dst16=ws+1*WS_SEG; }
    else if (z == 2) { A1=regs_bf; B1=Wt+262144; bias1=bk; epi=1; dst16=ws+2*WS_SEG; }
    else if (z == 3) { A1=grid_bf; B1=Wt+262144; bias1=bk; epi=1; dst16=ws+3*WS_SEG; }
    else if (z == 4) { A1=regs_bf; B1=Wt+524288; bias1=bv; epi=3; dst16=ws+4*WS_SEG; }
    else             { A1=grid_bf; B1=Wt+524288; bias1=bv; epi=3; dst16=ws+5*WS_SEG; }
  } else {
    if (z == 0) { A1=ws+6*WS_SEG; B1=Wt+1048576; bias1=bo1; epi=2; dst32=out; }
    else        { A1=ws+7*WS_SEG; B1=Wt+1310720; bias1=bo2; epi=2; dst32=out + 2097152; }
  }
  const bool swp = (epi == 3);

  const int t = threadIdx.x;
  const int lane = t & 63, w = t >> 6;
  const int l15 = lane & 15, q4 = lane >> 4;
  const int m0 = m_idx * MT, j0 = j_idx * 128;
  const int ro = (w >> 1) * (MT / 2), co = (w & 1) * 64;

  f32x4 acc[MFR][4];
  for (int i = 0; i < MFR; i++)
    for (int j = 0; j < 4; j++) acc[i][j] = (f32x4){0.f, 0.f, 0.f, 0.f};

  for (int k0 = 0; k0 < KT; k0 += 64) {
    const u16* pa; const u16* pb; int kk = k0, ra, rb;
    if (swp)           { pa = B1; pb = A1; ra = j0; rb = m0; }
    else if (kk < 512) { pa = A1; pb = B1; ra = m0; rb = j0; }
    else               { pa = A2; pb = B2; ra = m0; rb = j0; kk -= 512; }
    __syncthreads();
#pragma unroll
    for (int c = 0; c < MFR; c++) {
      const int cidx = w * MFR + c;
      const int row = cidx * 8 + (lane >> 3);
      const int cg = (lane & 7) ^ (row & 7);
      gld16(&pa[(size_t)(ra + row) * 512 + kk + cg * 8], &As[cidx * 512]);
    }
#pragma unroll
    for (int c = 0; c < 4; c++) {
      const int cidx = w * 4 + c;
      const int row = cidx * 8 + (lane >> 3);
      const int cg = (lane & 7) ^ (row & 7);
      gld16(&pb[(size_t)(rb + row) * 512 + kk + cg * 8], &Bs[cidx * 512]);
    }
    __syncthreads();
#pragma unroll
    for (int h = 0; h < 2; h++) {
      bf16x8 af[MFR], bfr[4];
#pragma unroll
      for (int i = 0; i < MFR; i++) {
        const int r = ro + i * 16 + l15;
        af[i] = *(const bf16x8*)&As[r * 64 + (((h * 4 + q4) ^ (r & 7)) * 8)];
      }
#pragma unroll
      for (int i = 0; i < 4; i++) {
        const int r = co + i * 16 + l15;
        bfr[i] = *(const bf16x8*)&Bs[r * 64 + (((h * 4 + q4) ^ (r & 7)) * 8)];
      }
#pragma unroll
      for (int mt = 0; mt < MFR; mt++)
#pragma unroll
        for (int nt = 0; nt < 4; nt++)
          acc[mt][nt] = __builtin_amdgcn_mfma_f32_16x16x32_bf16(af[mt], bfr[nt], acc[mt][nt], 0, 0, 0);
    }
  }

  if (epi == 2) {
    // f32 output, scalar dword stores (coalesced across l15)
#pragma unroll
    for (int nt = 0; nt < 4; nt++) {
      const int j = j0 + co + nt * 16 + l15;
      const float bsum = bias1[j];
#pragma unroll
      for (int mt = 0; mt < MFR; mt++)
#pragma unroll
        for (int r = 0; r < 4; r++) {
          const int m = m0 + ro + mt * 16 + q4 * 4 + r;
          dst32[m * 512 + j] = acc[mt][nt][r] + bsum;
        }
    }
    return;
  }

  // bf16 outputs: LDS round-trip -> coalesced dwordx4 stores.
  __syncthreads();                     // SM dead; reuse
  u16* Es = SM + w * (MT / 2) * 64;    // per-wave (MT/2) x 64 swizzled tile

  if (epi == 3) {
    // swapped: tile rows = hd (j0+ro+rr), cols = token (m0+co+cc)
#pragma unroll
    for (int mt = 0; mt < MFR; mt++)
#pragma unroll
      for (int r = 0; r < 4; r++) {
        const int rr = mt * 16 + q4 * 4 + r;
        const float bias = bias1[j0 + ro + rr];
#pragma unroll
        for (int nt = 0; nt < 4; nt++)
          Es[rr * 64 + (((nt * 2 + (l15 >> 3)) ^ (rr & 7)) * 8) + (l15 & 7)] =
              f2b(acc[mt][nt][r] + bias);
      }
  } else {
    float bsum4[4];
#pragma unroll
    for (int nt = 0; nt < 4; nt++) {
      const int j = j0 + co + nt * 16 + l15;
      bsum4[nt] = bias1[j] + (bias2 ? bias2[j] : 0.f);
    }
#pragma unroll
    for (int mt = 0; mt < MFR; mt++)
#pragma unroll
      for (int r = 0; r < 4; r++) {
        const int rr = mt * 16 + q4 * 4 + r;
        const float awm = (epi == 1) ? 0.18033688f * aw[m0 + ro + rr] : 1.f;
#pragma unroll
        for (int nt = 0; nt < 4; nt++)
          Es[rr * 64 + (((nt * 2 + (l15 >> 3)) ^ (rr & 7)) * 8) + (l15 & 7)] =
              f2b((acc[mt][nt][r] + bsum4[nt]) * awm);
      }
  }
  asm volatile("s_waitcnt lgkmcnt(0)" ::: "memory");  // wave-local RAW on Es

#pragma unroll
  for (int g = 0; g < MT / 16; g++) {
    const int rr2 = g * 8 + (lane >> 3);
    i32x4 val = *(const i32x4*)&Es[rr2 * 64 + (((lane & 7) ^ (rr2 & 7)) * 8)];
    if (epi == 3) {
      const int hd = j0 + ro + rr2;
      const int token0 = m0 + co;
      *(i32x4*)&dst16[((size_t)(token0 >> 11) * 512 + hd) * 2048 + (token0 & 2047) + (lane & 7) * 8] = val;
    } else {
      // head-major q/k: row = token, 64 cols = one head
      const int token = m0 + ro + rr2;
      const int bb = token >> 11, nn = token & 2047;
      const int h = (j0 + co) >> 6;
      *(i32x4*)&dst16[((size_t)(bb * 8 + h) * 2048 + nn) * 64 + (lane & 7) * 8] = val;
    }
  }
}

// ---------------------------------------------------------------------------
// Flash attention, fixed-max streaming softmax (exp2 domain, M=16 folded into
// mask bias). Block = 128 q-rows of one (path,b,h); wave = 32 rows.
// 1D grid with XCD swizzle: id%32 = bh_flat -> all q-tiles of one head share
// an XCD (K/V stay L2-resident). Single-buffered K/V staging (r6 structure).
// ---------------------------------------------------------------------------
__global__ __launch_bounds__(256, 2) void attn_kernel(
    const int* __restrict__ mask_r, const int* __restrict__ mask_g,
    u16* __restrict__ ws)
{
  const int id = blockIdx.x;
  const int bhf = id & 31;              // XCD = id%8 = bhf%8
  const int qt = id >> 5;
  const int path = bhf >> 4, bh = bhf & 15;
  const int b = bh >> 3, h = bh & 7;
  const u16* Q  = (path ? ws + 1 * WS_SEG : ws + 0 * WS_SEG) + (size_t)bh * (2048 * 64) + qt * 128 * 64;
  const u16* K  = (path ? ws + 3 * WS_SEG : ws + 2 * WS_SEG) + (size_t)bh * (2048 * 64);
  const u16* Vg = (path ? ws + 5 * WS_SEG : ws + 4 * WS_SEG) + (size_t)(b * 512 + h * 64) * 2048;
  const int* mask = (path ? mask_g : mask_r) + b * 2048;
  u16* O = (path ? ws + 7 * WS_SEG : ws + 6 * WS_SEG) + (size_t)(b * 2048 + qt * 128) * 512 + h * 64;

  __shared__ u16 Ks[64 * 64];     // [key][d], swizzled chunks
  __shared__ u16 Vs[64 * 64];     // [d][key], swizzled chunks
  __shared__ u16 Ps[128 * 64];    // XOR-swizzled P round-trip
  __shared__ float Ms[2048];      // mask bias - 16 (fixed max)

  const int t = threadIdx.x, lane = t & 63, w = t >> 6;
  const int l15 = lane & 15, q4 = lane >> 4;

  {
    const int4 a = *(const int4*)&mask[t * 8];
    const int4 c = *(const int4*)&mask[t * 8 + 4];
    float4 f1, f2v;
    f1.x = (a.x ? -1e30f : 0.f) - 16.f; f1.y = (a.y ? -1e30f : 0.f) - 16.f;
    f1.z = (a.z ? -1e30f : 0.f) - 16.f; f1.w = (a.w ? -1e30f : 0.f) - 16.f;
    f2v.x = (c.x ? -1e30f : 0.f) - 16.f; f2v.y = (c.y ? -1e30f : 0.f) - 16.f;
    f2v.z = (c.z ? -1e30f : 0.f) - 16.f; f2v.w = (c.w ? -1e30f : 0.f) - 16.f;
    *(float4*)&Ms[t * 8] = f1;
    *(float4*)&Ms[t * 8 + 4] = f2v;
  }

  bf16x8 qf[2][2];
#pragma unroll
  for (int mt = 0; mt < 2; mt++) {
    const int qrow = w * 32 + mt * 16 + l15;
    qf[mt][0] = *(const bf16x8*)&Q[qrow * 64 + q4 * 8];
    qf[mt][1] = *(const bf16x8*)&Q[qrow * 64 + 32 + q4 * 8];
  }

  float l_run[2][4];
  f32x4 o_acc[2][4];
#pragma unroll
  for (int mt = 0; mt < 2; mt++) {
#pragma unroll
    for (int r = 0; r < 4; r++) l_run[mt][r] = 0.f;
#pragma unroll
    for (int d = 0; d < 4; d++) o_acc[mt][d] = (f32x4){0.f, 0.f, 0.f, 0.f};
  }

  for (int kt = 0; kt < 32; kt++) {
    __syncthreads();
#pragma unroll
    for (int c = 0; c < 2; c++) {           // stage K and V^T (8 KB each)
      const int cidx = w * 2 + c;
      const int row = cidx * 8 + (lane >> 3);
      const int cg = (lane & 7) ^ (row & 7);
      gld16(&K[(size_t)(kt * 64 + row) * 64 + cg * 8], &Ks[cidx * 512]);
      gld16(&Vg[(size_t)row * 2048 + kt * 64 + cg * 8], &Vs[cidx * 512]);
    }
    __syncthreads();

    // S = Q K^T (scale*log2e*aw pre-folded into K)
    f32x4 s[2][4];
#pragma unroll
    for (int mt = 0; mt < 2; mt++)
#pragma unroll
      for (int nt = 0; nt < 4; nt++) s[mt][nt] = (f32x4){0.f, 0.f, 0.f, 0.f};
#pragma unroll
    for (int nt = 0; nt < 4; nt++)
#pragma unroll
      for (int ss = 0; ss < 2; ss++) {
        const int r = nt * 16 + l15;
        bf16x8 kf = *(const bf16x8*)&Ks[r * 64 + (((ss * 4 + q4) ^ (r & 7)) * 8)];
        s[0][nt] = __builtin_amdgcn_mfma_f32_16x16x32_bf16(qf[0][ss], kf, s[0][nt], 0, 0, 0);
        s[1][nt] = __builtin_amdgcn_mfma_f32_16x16x32_bf16(qf[1][ss], kf, s[1][nt], 0, 0, 0);
      }

    // p = exp2(s + maskbias - 16); accumulate per-lane l; no max tracking
#pragma unroll
    for (int nt = 0; nt < 4; nt++) {
      const float bias = Ms[kt * 64 + nt * 16 + l15];
#pragma unroll
      for (int mt = 0; mt < 2; mt++)
#pragma unroll
        for (int r = 0; r < 4; r++) {
          const float p = fexp2(s[mt][nt][r] + bias);
          s[mt][nt][r] = p;
          l_run[mt][r] += p;
        }
    }

    // P: C-layout -> A-layout via XOR-swizzled per-wave LDS round trip
#pragma unroll
    for (int mt = 0; mt < 2; mt++)
#pragma unroll
      for (int nt = 0; nt < 4; nt++) {
        const int cg = 2 * nt + (l15 >> 3);
#pragma unroll
        for (int r = 0; r < 4; r++) {
          const int row = w * 32 + mt * 16 + q4 * 4 + r;
          Ps[row * 64 + ((cg ^ (row & 7)) * 8) + (l15 & 7)] = f2b(s[mt][nt][r]);
        }
      }
    asm volatile("s_waitcnt lgkmcnt(0)" ::: "memory");  // wave-local RAW on Ps

    // O += P V
#pragma unroll
    for (int ss = 0; ss < 2; ss++) {
      bf16x8 pf[2];
#pragma unroll
      for (int mt = 0; mt < 2; mt++) {
        const int row = w * 32 + mt * 16 + l15;
        const int cg = (4 * ss + q4) ^ (row & 7);
        pf[mt] = *(const bf16x8*)&Ps[row * 64 + cg * 8];
      }
#pragma unroll
      for (int dt = 0; dt < 4; dt++) {
        const int r = dt * 16 + l15;
        bf16x8 vf = *(const bf16x8*)&Vs[r * 64 + (((ss * 4 + q4) ^ (r & 7)) * 8)];
        o_acc[0][dt] = __builtin_amdgcn_mfma_f32_16x16x32_bf16(pf[0], vf, o_acc[0][dt], 0, 0, 0);
        o_acc[1][dt] = __builtin_amdgcn_mfma_f32_16x16x32_bf16(pf[1], vf, o_acc[1][dt], 0, 0, 0);
      }
    }
  }

  // O /= l, scalar stores (r6 epilogue)
#pragma unroll
  for (int mt = 0; mt < 2; mt++)
#pragma unroll
    for (int r = 0; r < 4; r++) {
      const float inv = 1.f / rowsum16(l_run[mt][r]);
#pragma unroll
      for (int dt = 0; dt < 4; dt++) {
        O[(w * 32 + mt * 16 + q4 * 4 + r) * 512 + dt * 16 + l15] = f2b(o_acc[mt][dt][r] * inv);
      }
    }
}

extern "C" void kernel_launch(void* const* d_in, const int* in_sizes, int n_in,
                              void* d_out, int out_size, void* d_ws, size_t ws_size,
                              hipStream_t stream) {
  const float* regions   = (const float*)d_in[0];
  const float* grids     = (const float*)d_in[1];
  const float* interests = (const float*)d_in[2];
  const int*   mask_r    = (const int*)d_in[3];
  const int*   mask_g    = (const int*)d_in[4];
  const float* aw        = (const float*)d_in[5];
  const float* Wq  = (const float*)d_in[6];  const float* bq  = (const float*)d_in[7];
  const float* Wk  = (const float*)d_in[8];  const float* bk  = (const float*)d_in[9];
  const float* Wv  = (const float*)d_in[10]; const float* bv  = (const float*)d_in[11];
  const float* Wq12= (const float*)d_in[12]; const float* bq12= (const float*)d_in[13];
  const float* Wo1 = (const float*)d_in[14]; const float* bo1 = (const float*)d_in[15];
  const float* Wo2 = (const float*)d_in[16]; const float* bo2 = (const float*)d_in[17];
  u16*   ws  = (u16*)d_ws;
  float* out = (float*)d_out;

  // 0) f32 -> bf16 pre-convert (activations + weights)
  convert_kernel<<<3840, 256, 0, stream>>>(regions, grids, interests,
      Wq, Wk, Wv, Wq12, Wo1, Wo2, ws);
  // 1) projections: 1D grid 768 = 32 m x 4 j x 6 z, XCD-swizzled
  gemm_all<128, 32><<<768, 256, 0, stream>>>(aw, bq, bk, bv, bq12, bo1, bo2,
      ws, out, 0);
  // 2) flash attention: 1D grid 512 = 32 bh-combos x 16 q-tiles, XCD-swizzled
  attn_kernel<<<512, 256, 0, stream>>>(mask_r, mask_g, ws);
  // 3) output projections: 1D grid 512 = 64 m x 4 j x 2 z -> f32 d_out
  gemm_all<64, 64><<<512, 256, 0, stream>>>(aw, bq, bk, bv, bq12, bo1, bo2,
      ws, out, 1);
}

// Round 11
// 176.336 us; speedup vs baseline: 1.2401x; 1.1032x over previous
//
#include <hip/hip_runtime.h>
#include <hip/hip_bf16.h>

typedef __attribute__((ext_vector_type(8))) __bf16 bf16x8;
typedef __attribute__((ext_vector_type(4))) float f32x4;
typedef __attribute__((ext_vector_type(4))) int   i32x4;
typedef unsigned short u16;

// B=2, N=2048, D_MODEL=512, H=8, DK=DV=64. I/O f32; ws intermediates bf16.
// ws (u16 elems), 10 segs x 2M:
//  0 qA  1 qB  2 k1  3 k2   (head-major, k compacted: [b*8+h][i][64])
//  4 v1^T 5 v2^T            (compacted cols: [b*512+h*64+d][i])
//  6 regions_bf (later O1 token-major)  7 grids_bf (later O2)  8 interests_bf
//  9 weights Wq/Wk/Wv/Wq12/Wo1/Wo2 (1572864 elems), tail: idx[4][2048] int +
//    Nc[4] int  (compaction tables, built by scan_kernel)
#define WS_SEG 2097152
#define TAIL_OFF (9 * WS_SEG + 1572864)

static __device__ __forceinline__ u16 f2b(float f) {
  __hip_bfloat16 h = __float2bfloat16(f);  // RNE
  return __builtin_bit_cast(u16, h);
}
static __device__ __forceinline__ i32x4 cvt8(const float* __restrict__ p) {
  float4 a = *(const float4*)p;
  float4 b = *(const float4*)(p + 4);
  union { i32x4 v; u16 u[8]; } r;
  r.u[0]=f2b(a.x); r.u[1]=f2b(a.y); r.u[2]=f2b(a.z); r.u[3]=f2b(a.w);
  r.u[4]=f2b(b.x); r.u[5]=f2b(b.y); r.u[6]=f2b(b.z); r.u[7]=f2b(b.w);
  return r.v;
}
static __device__ __forceinline__ float fexp2(float x) {
  float r; asm("v_exp_f32 %0, %1" : "=v"(r) : "v"(x)); return r;
}
template<int C>
static __device__ __forceinline__ float dppf(float x) {
  int v = __builtin_amdgcn_update_dpp(__builtin_bit_cast(int, x),
                                      __builtin_bit_cast(int, x), C, 0xF, 0xF, false);
  return __builtin_bit_cast(float, v);
}
static __device__ __forceinline__ float rowsum16(float x) {
  x += dppf<0xB1>(x);    // xor1
  x += dppf<0x4E>(x);    // xor2
  x += dppf<0x141>(x);   // row_half_mirror
  x += dppf<0x140>(x);   // row_mirror
  return x;
}
// async 16B global -> LDS (dest = wave-uniform base + lane*16; SOURCE may
// scatter per-lane)
static __device__ __forceinline__ void gld16(const u16* gp, u16* lp) {
  __builtin_amdgcn_global_load_lds(
      (const __attribute__((address_space(1))) void*)gp,
      (__attribute__((address_space(3))) void*)lp, 16, 0, 0);
}

// ---------------------------------------------------------------------------
// Scan: per (path,b) order-preserving compaction of unmasked keys.
// idx[pb][i] = token of i-th unmasked key (0-padded); Nc[pb] = count.
// ---------------------------------------------------------------------------
__global__ __launch_bounds__(256) void scan_kernel(
    const int* __restrict__ mask_r, const int* __restrict__ mask_g,
    u16* __restrict__ ws)
{
  const int pb = blockIdx.x;            // path*2 + b
  const int path = pb >> 1, b = pb & 1;
  const int* mask = (path ? mask_g : mask_r) + b * 2048;
  int* base = (int*)(ws + TAIL_OFF);
  int* idx = base + pb * 2048;
  int* NcArr = base + 4 * 2048;

  __shared__ int sc[256];
  const int t = threadIdx.x;
  int m[8];
#pragma unroll
  for (int j = 0; j < 8; j++) m[j] = mask[t * 8 + j];
  int cnt = 0;
#pragma unroll
  for (int j = 0; j < 8; j++) cnt += (m[j] == 0);
  sc[t] = cnt;
  __syncthreads();
  for (int d = 1; d < 256; d <<= 1) {   // Hillis-Steele inclusive scan
    int v = (t >= d) ? sc[t - d] : 0;
    __syncthreads();
    sc[t] += v;
    __syncthreads();
  }
  int off = sc[t] - cnt;
  const int Nc = sc[255];
#pragma unroll
  for (int j = 0; j < 8; j++)
    if (m[j] == 0) idx[off++] = t * 8 + j;
  for (int j = Nc + t; j < 2048; j += 256) idx[j] = 0;   // safe pad
  if (t == 0) NcArr[pb] = Nc;
}

// ---------------------------------------------------------------------------
// Pre-convert f32 -> bf16 into ws (activations + weights)
// ---------------------------------------------------------------------------
__global__ __launch_bounds__(256) void convert_kernel(
    const float* __restrict__ regions, const float* __restrict__ grids,
    const float* __restrict__ interests,
    const float* __restrict__ Wq, const float* __restrict__ Wk,
    const float* __restrict__ Wv, const float* __restrict__ Wq12,
    const float* __restrict__ Wo1, const float* __restrict__ Wo2,
    u16* __restrict__ ws)
{
  const size_t i = (size_t)(blockIdx.x * 256 + threadIdx.x) * 8;
  const float* s; u16* d;
  if (i < 2097152)      { s = regions   + i;           d = ws + 6 * WS_SEG + i; }
  else if (i < 4194304) { s = grids     + (i - 2097152); d = ws + 7 * WS_SEG + (i - 2097152); }
  else if (i < 6291456) { s = interests + (i - 4194304); d = ws + 8 * WS_SEG + (i - 4194304); }
  else {
    const size_t j = i - 6291456;          // 0 .. 1572863
    d = ws + 9 * WS_SEG + j;
    if (j < 262144)       s = Wq  + j;
    else if (j < 524288)  s = Wk  + (j - 262144);
    else if (j < 786432)  s = Wv  + (j - 524288);
    else if (j < 1048576) s = Wq12+ (j - 786432);
    else if (j < 1310720) s = Wo1 + (j - 1048576);
    else                  s = Wo2 + (j - 1310720);
  }
  *(i32x4*)d = cvt8(s);
}

// ---------------------------------------------------------------------------
// bt-GEMM, MTx128 tile, BK=64, 4 waves, single-buffered m97 loop,
// global_load_lds staging, XOR-swizzled stride-64 LDS rows, 1D XCD-swizzled
// grid (id%NM = m_idx). k/v projections (z>=2) run in COMPACTED key space:
// A-side (k) / B-side (v) rows gathered via idx[], pad rows zeroed.
// phase 0 (MT=128, NM=32): z0 qA (K=1024 concat), z1 qB, z2 k1 (*s*log2e*aw),
//                          z3 k2, z4 v1^T (swapped), z5 v2^T
// phase 1 (MT=64,  NM=64): z0/z1 out = O_z @ Wo_z^T + bo_z -> f32 d_out
// ---------------------------------------------------------------------------
template<int MT, int NM>
__global__ __launch_bounds__(256, 2) void gemm_all(
    const float* __restrict__ aw,
    const float* __restrict__ bq,  const float* __restrict__ bk,
    const float* __restrict__ bv,  const float* __restrict__ bq12,
    const float* __restrict__ bo1, const float* __restrict__ bo2,
    u16* __restrict__ ws, float* __restrict__ out, int phase)
{
  constexpr int MFR = MT / 32;       // m-frags per wave
  __shared__ u16 SM[(MT + 128) * 64];
  u16* As = SM;
  u16* Bs = SM + MT * 64;

  const u16* regs_bf = ws + 6 * WS_SEG;
  const u16* grid_bf = ws + 7 * WS_SEG;
  const u16* intr_bf = ws + 8 * WS_SEG;
  const u16* Wt      = ws + 9 * WS_SEG;

  const int id = blockIdx.x;
  const int m_idx = id % NM;
  const int rest  = id / NM;
  const int j_idx = rest & 3;
  const int z     = rest >> 2;

  const u16 *A1 = nullptr, *A2 = nullptr, *B1 = nullptr, *B2 = nullptr;
  const float *bias1 = nullptr, *bias2 = nullptr;
  u16* dst16 = nullptr;
  float* dst32 = nullptr;
  int KT = 512, epi = 0;
  if (phase == 0) {
    if (z == 0)      { A1=intr_bf; A2=grid_bf; B1=Wt; B2=Wt+786432; KT=1024; bias1=bq; bias2=bq12; epi=0; dst16=ws+0*WS_SEG; }
    else if (z == 1) { A1=intr_bf; A2=regs_bf; B1=Wt; B2=Wt+786432; KT=1024; bias1=bq; bias2=bq12; epi=0; dst16=ws+1*WS_SEG; }
    else if (z == 2) { A1=regs_bf; B1=Wt+262144; bias1=bk; epi=1; dst16=ws+2*WS_SEG; }
    else if (z == 3) { A1=grid_bf; B1=Wt+262144; bias1=bk; epi=1; dst16=ws+3*WS_SEG; }
    else if (z == 4) { A1=regs_bf; B1=Wt+524288; bias1=bv; epi=3; dst16=ws+4*WS_SEG; }
    else             { A1=grid_bf; B1=Wt+524288; bias1=bv; epi=3; dst16=ws+5*WS_SEG; }
  } else {
    if (z == 0) { A1=ws+6*WS_SEG; B1=Wt+1048576; bias1=bo1; epi=2; dst32=out; }
    else        { A1=ws+7*WS_SEG; B1=Wt+1310720; bias1=bo2; epi=2; dst32=out + 2097152; }
  }
  const bool swp = (epi == 3);

  // compaction info for k/v projections
  int Nc = 1 << 30, mloc = 0, bb = 0;
  const int* gidx = nullptr;
  if (phase == 0 && z >= 2) {
    const int path = (z == 3 || z == 5) ? 1 : 0;
    bb = m_idx >> 4;                       // 16 m-tiles per batch
    const int* base = (const int*)(ws + TAIL_OFF);
    gidx = base + (path * 2 + bb) * 2048;
    Nc = base[4 * 2048 + path * 2 + bb];
    mloc = (m_idx & 15) * 128;
    if (mloc >= ((Nc + 127) & ~127)) return;   // uniform exit
  }

  const int t = threadIdx.x;
  const int lane = t & 63, w = t >> 6;
  const int l15 = lane & 15, q4 = lane >> 4;
  const int m0 = (gidx ? mloc : m_idx * MT), j0 = j_idx * 128;
  const int ro = (w >> 1) * (MT / 2), co = (w & 1) * 64;

  // hoisted staging rows (gather for compacted activations)
  int arows[MFR], brows[4];
#pragma unroll
  for (int c = 0; c < MFR; c++) {
    const int row = (w * MFR + c) * 8 + (lane >> 3);
    if (swp)            arows[c] = j0 + row;                       // weights
    else if (gidx)      arows[c] = bb * 2048 + gidx[m0 + row];     // k gather
    else                arows[c] = m0 + row;
  }
#pragma unroll
  for (int c = 0; c < 4; c++) {
    const int row = (w * 4 + c) * 8 + (lane >> 3);
    if (!swp)           brows[c] = j0 + row;                       // weights
    else if (gidx)      brows[c] = bb * 2048 + gidx[m0 + row];     // v gather
    else                brows[c] = m0 + row;
  }

  f32x4 acc[MFR][4];
  for (int i = 0; i < MFR; i++)
    for (int j = 0; j < 4; j++) acc[i][j] = (f32x4){0.f, 0.f, 0.f, 0.f};

  for (int k0 = 0; k0 < KT; k0 += 64) {
    const u16* pa; const u16* pb; int kk = k0;
    if (swp)           { pa = B1; pb = A1; }
    else if (kk < 512) { pa = A1; pb = B1; }
    else               { pa = A2; pb = B2; kk -= 512; }
    __syncthreads();
#pragma unroll
    for (int c = 0; c < MFR; c++) {
      const int cidx = w * MFR + c;
      const int row = cidx * 8 + (lane >> 3);
      const int cg = (lane & 7) ^ (row & 7);
      gld16(&pa[(size_t)arows[c] * 512 + kk + cg * 8], &As[cidx * 512]);
    }
#pragma unroll
    for (int c = 0; c < 4; c++) {
      const int cidx = w * 4 + c;
      const int row = cidx * 8 + (lane >> 3);
      const int cg = (lane & 7) ^ (row & 7);
      gld16(&pb[(size_t)brows[c] * 512 + kk + cg * 8], &Bs[cidx * 512]);
    }
    __syncthreads();
#pragma unroll
    for (int h = 0; h < 2; h++) {
      bf16x8 af[MFR], bfr[4];
#pragma unroll
      for (int i = 0; i < MFR; i++) {
        const int r = ro + i * 16 + l15;
        af[i] = *(const bf16x8*)&As[r * 64 + (((h * 4 + q4) ^ (r & 7)) * 8)];
      }
#pragma unroll
      for (int i = 0; i < 4; i++) {
        const int r = co + i * 16 + l15;
        bfr[i] = *(const bf16x8*)&Bs[r * 64 + (((h * 4 + q4) ^ (r & 7)) * 8)];
      }
#pragma unroll
      for (int mt = 0; mt < MFR; mt++)
#pragma unroll
        for (int nt = 0; nt < 4; nt++)
          acc[mt][nt] = __builtin_amdgcn_mfma_f32_16x16x32_bf16(af[mt], bfr[nt], acc[mt][nt], 0, 0, 0);
    }
  }

  if (epi == 2) {
    // f32 output, scalar dword stores (coalesced across l15)
#pragma unroll
    for (int nt = 0; nt < 4; nt++) {
      const int j = j0 + co + nt * 16 + l15;
      const float bsum = bias1[j];
#pragma unroll
      for (int mt = 0; mt < MFR; mt++)
#pragma unroll
        for (int r = 0; r < 4; r++) {
          const int m = m0 + ro + mt * 16 + q4 * 4 + r;
          dst32[m * 512 + j] = acc[mt][nt][r] + bsum;
        }
    }
    return;
  }

  // bf16 outputs: LDS round-trip -> coalesced dwordx4 stores.
  __syncthreads();                     // SM dead; reuse
  u16* Es = SM + w * (MT / 2) * 64;    // per-wave (MT/2) x 64 swizzled tile

  if (epi == 3) {
    // swapped: tile rows = hd (j0+ro+rr), cols = compact token (m0+co+cc)
#pragma unroll
    for (int mt = 0; mt < MFR; mt++)
#pragma unroll
      for (int r = 0; r < 4; r++) {
        const int rr = mt * 16 + q4 * 4 + r;
        const float bias = bias1[j0 + ro + rr];
#pragma unroll
        for (int nt = 0; nt < 4; nt++) {
          const int col = m0 + co + nt * 16 + l15;   // compact index
          const float v = acc[mt][nt][r] + bias;
          Es[rr * 64 + (((nt * 2 + (l15 >> 3)) ^ (rr & 7)) * 8) + (l15 & 7)] =
              (col < Nc) ? f2b(v) : (u16)0;          // zero pad cols
        }
      }
  } else {
    float bsum4[4];
#pragma unroll
    for (int nt = 0; nt < 4; nt++) {
      const int j = j0 + co + nt * 16 + l15;
      bsum4[nt] = bias1[j] + (bias2 ? bias2[j] : 0.f);
    }
#pragma unroll
    for (int mt = 0; mt < MFR; mt++)
#pragma unroll
      for (int r = 0; r < 4; r++) {
        const int rr = mt * 16 + q4 * 4 + r;
        const int i = m0 + ro + rr;                  // compact index (epi==1)
        float awm = 1.f;
        if (epi == 1) awm = 0.18033688f * aw[bb * 2048 + gidx[i]];
#pragma unroll
        for (int nt = 0; nt < 4; nt++) {
          const float v = (acc[mt][nt][r] + bsum4[nt]) * awm;
          Es[rr * 64 + (((nt * 2 + (l15 >> 3)) ^ (rr & 7)) * 8) + (l15 & 7)] =
              (i < Nc) ? f2b(v) : (u16)0;            // zero pad rows
        }
      }
  }
  asm volatile("s_waitcnt lgkmcnt(0)" ::: "memory");  // wave-local RAW on Es

#pragma unroll
  for (int g = 0; g < MT / 16; g++) {
    const int rr2 = g * 8 + (lane >> 3);
    i32x4 val = *(const i32x4*)&Es[rr2 * 64 + (((lane & 7) ^ (rr2 & 7)) * 8)];
    if (epi == 3) {
      const int hd = j0 + ro + rr2;
      const int tok0 = m0 + co;                      // compact col base
      *(i32x4*)&dst16[((size_t)(bb * 512) + hd) * 2048 + tok0 + (lane & 7) * 8] = val;
    } else if (epi == 1) {
      const int i = m0 + ro + rr2;                   // compact row
      const int hh = (j0 + co) >> 6;
      *(i32x4*)&dst16[((size_t)(bb * 8 + hh) * 2048 + i) * 64 + (lane & 7) * 8] = val;
    } else {
      // head-major q: row = token, 64 cols = one head
      const int token = m0 + ro + rr2;
      const int b2 = token >> 11, nn = token & 2047;
      const int hh = (j0 + co) >> 6;
      *(i32x4*)&dst16[((size_t)(b2 * 8 + hh) * 2048 + nn) * 64 + (lane & 7) * 8] = val;
    }
  }
}

// ---------------------------------------------------------------------------
// Flash attention over COMPACTED keys: loop ceil(Nc/64) tiles; pad keys get
// bias -1e30 (k,v pad rows zeroed by projections). Fixed-max exp2 softmax.
// Block = 128 q-rows of one (path,b,h); 1D grid, id%32 = bh-combo (XCD local).
// ---------------------------------------------------------------------------
__global__ __launch_bounds__(256, 2) void attn_kernel(u16* __restrict__ ws)
{
  const int id = blockIdx.x;
  const int bhf = id & 31;              // XCD = id%8 = bhf%8
  const int qt = id >> 5;
  const int path = bhf >> 4, bh = bhf & 15;
  const int b = bh >> 3, h = bh & 7;
  const u16* Q  = (path ? ws + 1 * WS_SEG : ws + 0 * WS_SEG) + (size_t)bh * (2048 * 64) + qt * 128 * 64;
  const u16* K  = (path ? ws + 3 * WS_SEG : ws + 2 * WS_SEG) + (size_t)bh * (2048 * 64);
  const u16* Vg = (path ? ws + 5 * WS_SEG : ws + 4 * WS_SEG) + (size_t)(b * 512 + h * 64) * 2048;
  u16* O = (path ? ws + 7 * WS_SEG : ws + 6 * WS_SEG) + (size_t)(b * 2048 + qt * 128) * 512 + h * 64;

  const int* base = (const int*)(ws + TAIL_OFF);
  const int Nc = base[4 * 2048 + path * 2 + b];
  const int ktm = (Nc + 63) >> 6;

  __shared__ u16 Ks[64 * 64];     // [key][d], swizzled chunks
  __shared__ u16 Vs[64 * 64];     // [d][key], swizzled chunks
  __shared__ u16 Ps[128 * 64];    // XOR-swizzled P round-trip

  const int t = threadIdx.x, lane = t & 63, w = t >> 6;
  const int l15 = lane & 15, q4 = lane >> 4;

  bf16x8 qf[2][2];
#pragma unroll
  for (int mt = 0; mt < 2; mt++) {
    const int qrow = w * 32 + mt * 16 + l15;
    qf[mt][0] = *(const bf16x8*)&Q[qrow * 64 + q4 * 8];
    qf[mt][1] = *(const bf16x8*)&Q[qrow * 64 + 32 + q4 * 8];
  }

  float l_run[2][4];
  f32x4 o_acc[2][4];
#pragma unroll
  for (int mt = 0; mt < 2; mt++) {
#pragma unroll
    for (int r = 0; r < 4; r++) l_run[mt][r] = 0.f;
#pragma unroll
    for (int d = 0; d < 4; d++) o_acc[mt][d] = (f32x4){0.f, 0.f, 0.f, 0.f};
  }

  for (int kt = 0; kt < ktm; kt++) {
    __syncthreads();
#pragma unroll
    for (int c = 0; c < 2; c++) {           // stage K and V^T (8 KB each)
      const int cidx = w * 2 + c;
      const int row = cidx * 8 + (lane >> 3);
      const int cg = (lane & 7) ^ (row & 7);
      gld16(&K[(size_t)(kt * 64 + row) * 64 + cg * 8], &Ks[cidx * 512]);
      gld16(&Vg[(size_t)row * 2048 + kt * 64 + cg * 8], &Vs[cidx * 512]);
    }
    __syncthreads();

    // S = Q K^T (scale*log2e*aw pre-folded into K)
    f32x4 s[2][4];
#pragma unroll
    for (int mt = 0; mt < 2; mt++)
#pragma unroll
      for (int nt = 0; nt < 4; nt++) s[mt][nt] = (f32x4){0.f, 0.f, 0.f, 0.f};
#pragma unroll
    for (int nt = 0; nt < 4; nt++)
#pragma unroll
      for (int ss = 0; ss < 2; ss++) {
        const int r = nt * 16 + l15;
        bf16x8 kf = *(const bf16x8*)&Ks[r * 64 + (((ss * 4 + q4) ^ (r & 7)) * 8)];
        s[0][nt] = __builtin_amdgcn_mfma_f32_16x16x32_bf16(qf[0][ss], kf, s[0][nt], 0, 0, 0);
        s[1][nt] = __builtin_amdgcn_mfma_f32_16x16x32_bf16(qf[1][ss], kf, s[1][nt], 0, 0, 0);
      }

    // p = exp2(s + bias); bias = -16 for live keys, -1e30 for pad
#pragma unroll
    for (int nt = 0; nt < 4; nt++) {
      const int kg = kt * 64 + nt * 16 + l15;
      const float bias = (kg < Nc) ? -16.f : -1e30f;
#pragma unroll
      for (int mt = 0; mt < 2; mt++)
#pragma unroll
        for (int r = 0; r < 4; r++) {
          const float p = fexp2(s[mt][nt][r] + bias);
          s[mt][nt][r] = p;
          l_run[mt][r] += p;
        }
    }

    // P: C-layout -> A-layout via XOR-swizzled per-wave LDS round trip
#pragma unroll
    for (int mt = 0; mt < 2; mt++)
#pragma unroll
      for (int nt = 0; nt < 4; nt++) {
        const int cg = 2 * nt + (l15 >> 3);
#pragma unroll
        for (int r = 0; r < 4; r++) {
          const int row = w * 32 + mt * 16 + q4 * 4 + r;
          Ps[row * 64 + ((cg ^ (row & 7)) * 8) + (l15 & 7)] = f2b(s[mt][nt][r]);
        }
      }
    asm volatile("s_waitcnt lgkmcnt(0)" ::: "memory");  // wave-local RAW on Ps

    // O += P V
#pragma unroll
    for (int ss = 0; ss < 2; ss++) {
      bf16x8 pf[2];
#pragma unroll
      for (int mt = 0; mt < 2; mt++) {
        const int row = w * 32 + mt * 16 + l15;
        const int cg = (4 * ss + q4) ^ (row & 7);
        pf[mt] = *(const bf16x8*)&Ps[row * 64 + cg * 8];
      }
#pragma unroll
      for (int dt = 0; dt < 4; dt++) {
        const int r = dt * 16 + l15;
        bf16x8 vf = *(const bf16x8*)&Vs[r * 64 + (((ss * 4 + q4) ^ (r & 7)) * 8)];
        o_acc[0][dt] = __builtin_amdgcn_mfma_f32_16x16x32_bf16(pf[0], vf, o_acc[0][dt], 0, 0, 0);
        o_acc[1][dt] = __builtin_amdgcn_mfma_f32_16x16x32_bf16(pf[1], vf, o_acc[1][dt], 0, 0, 0);
      }
    }
  }

  // O /= l, scalar stores
#pragma unroll
  for (int mt = 0; mt < 2; mt++)
#pragma unroll
    for (int r = 0; r < 4; r++) {
      const float inv = 1.f / rowsum16(l_run[mt][r]);
#pragma unroll
      for (int dt = 0; dt < 4; dt++) {
        O[(w * 32 + mt * 16 + q4 * 4 + r) * 512 + dt * 16 + l15] = f2b(o_acc[mt][dt][r] * inv);
      }
    }
}

extern "C" void kernel_launch(void* const* d_in, const int* in_sizes, int n_in,
                              void* d_out, int out_size, void* d_ws, size_t ws_size,
                              hipStream_t stream) {
  const float* regions   = (const float*)d_in[0];
  const float* grids     = (const float*)d_in[1];
  const float* interests = (const float*)d_in[2];
  const int*   mask_r    = (const int*)d_in[3];
  const int*   mask_g    = (const int*)d_in[4];
  const float* aw        = (const float*)d_in[5];
  const float* Wq  = (const float*)d_in[6];  const float* bq  = (const float*)d_in[7];
  const float* Wk  = (const float*)d_in[8];  const float* bk  = (const float*)d_in[9];
  const float* Wv  = (const float*)d_in[10]; const float* bv  = (const float*)d_in[11];
  const float* Wq12= (const float*)d_in[12]; const float* bq12= (const float*)d_in[13];
  const float* Wo1 = (const float*)d_in[14]; const float* bo1 = (const float*)d_in[15];
  const float* Wo2 = (const float*)d_in[16]; const float* bo2 = (const float*)d_in[17];
  u16*   ws  = (u16*)d_ws;
  float* out = (float*)d_out;

  // 0a) key compaction tables (masks only)
  scan_kernel<<<4, 256, 0, stream>>>(mask_r, mask_g, ws);
  // 0b) f32 -> bf16 pre-convert (activations + weights)
  convert_kernel<<<3840, 256, 0, stream>>>(regions, grids, interests,
      Wq, Wk, Wv, Wq12, Wo1, Wo2, ws);
  // 1) projections (k/v in compacted key space; ~half the k/v blocks exit)
  gemm_all<128, 32><<<768, 256, 0, stream>>>(aw, bq, bk, bv, bq12, bo1, bo2,
      ws, out, 0);
  // 2) flash attention over compacted keys (ceil(Nc/64) tiles)
  attn_kernel<<<512, 256, 0, stream>>>(ws);
  // 3) output projections -> f32 d_out
  gemm_all<64, 64><<<512, 256, 0, stream>>>(aw, bq, bk, bv, bq12, bo1, bo2,
      ws, out, 1);
}